// Round 4
// baseline (60.257 us; speedup 1.0000x reference)
//
#include <hip/hip_runtime.h>
#include <hip/hip_bf16.h>
#include <math.h>

#define B_ 4
#define L_ 2048
#define H_ 8
#define E_ 64
#define HE 512   // H_*E_ : float stride between consecutive seq positions

typedef short bf16x8 __attribute__((ext_vector_type(8)));
typedef float f32x4 __attribute__((ext_vector_type(4)));
typedef float f32x2 __attribute__((ext_vector_type(2)));
typedef unsigned short u16x4 __attribute__((ext_vector_type(4)));
typedef unsigned short u16x8 __attribute__((ext_vector_type(8)));

__device__ __forceinline__ unsigned short f2b(float f) {
  return __builtin_bit_cast(unsigned short, (__hip_bfloat16)f);
}

// Flash attention fwd, causal, tau-scaled.
// Block = 8 waves = 128 q-rows (16/wave). KV tile 64, double-buffered LDS.
// Swapped QK^T: sacc[m][r] = S[kv=64t+16m+4lg+r][q=q0w+ll] -> lane-local
// softmax; P feeds PV directly via kv-permuted k-slots (no P round-trip).
// R4: union V-frag loads (no repack), defer-max (T13, THR=8 in log2),
// setprio around MFMA (T5), balanced max/sum trees.
__global__ __launch_bounds__(512, 4) void attn_fwd(
    const float* __restrict__ Q, const float* __restrict__ K,
    const float* __restrict__ V, const float* __restrict__ tau,
    float* __restrict__ O)
{
  // balanced remap: CU c gets flat {c, c+256} -> qt {j, 15-j}; (b,h) per
  // flat%32 -> all q-tiles of one (b,h) on one XCD.
  const int f  = blockIdx.x + 16 * (blockIdx.y + 8 * blockIdx.z);
  const int u  = f >> 5, hb = f & 31;
  const int h  = hb & 7, b = hb >> 3;
  const int qt = (u < 8) ? u : 23 - u;

  const int tid  = threadIdx.x;
  const int wave = tid >> 6, lane = tid & 63;
  const int lg = lane >> 4, ll = lane & 15;
  const int llm = ll & 7;

  __shared__ unsigned short ldsK[2][64 * 64];  // [kv][e], swizzled
  __shared__ unsigned short ldsV[2][64 * 64];  // transposed [d][kv], swizzled

  const float qscale = 0.125f * expf(tau[b]) * 1.44269504088896f;
  const int q0w = qt * 128 + wave * 16;

  const float* Qb = Q + (((size_t)b * L_ + (q0w + ll)) * H_ + h) * E_;
  bf16x8 qf[2];
  #pragma unroll
  for (int ek = 0; ek < 2; ++ek) {
    f32x4 a = *(const f32x4*)(Qb + ek * 32 + lg * 8);
    f32x4 c = *(const f32x4*)(Qb + ek * 32 + lg * 8 + 4);
    #pragma unroll
    for (int j = 0; j < 4; ++j) {
      qf[ek][j]     = (short)f2b(a[j] * qscale);
      qf[ek][4 + j] = (short)f2b(c[j] * qscale);
    }
  }

  float m_run = -INFINITY, l_run = 0.0f;   // stats of q = q0w+ll (per lane)
  f32x4 oacc[4];
  #pragma unroll
  for (int n = 0; n < 4; ++n) {
    oacc[n][0] = 0.f; oacc[n][1] = 0.f; oacc[n][2] = 0.f; oacc[n][3] = 0.f;
  }

  // staging maps: K: row=tid>>3, cols (tid&7)*8..+7; V: rows 4*(tid>>5)+i,
  // cols (tid&31)*2..+1
  const int krow = tid >> 3;
  const int vq = tid >> 5,  vc = (tid & 31) * 2;
  const float* Kp = K + ((size_t)b * L_ * H_ + h) * E_ + (size_t)krow * HE + (tid & 7) * 8;
  const float* Vp = V + ((size_t)b * L_ * H_ + h) * E_ + (size_t)(4 * vq) * HE + vc;
  const int kw_off = krow * 64 + (((tid & 7) ^ (krow & 7)) << 3);

  const int nt = 2 * qt + 2;
  const int tmaxw = 2 * qt + (wave >> 2);  // this wave's diagonal tile

  // ---- prologue: stage tile 0 into buf 0 ----
  {
    f32x4 k0 = *(const f32x4*)(Kp);
    f32x4 k1 = *(const f32x4*)(Kp + 4);
    f32x2 v0 = *(const f32x2*)(Vp);
    f32x2 v1 = *(const f32x2*)(Vp + HE);
    f32x2 v2 = *(const f32x2*)(Vp + 2 * HE);
    f32x2 v3 = *(const f32x2*)(Vp + 3 * HE);
    u16x8 kw;
    #pragma unroll
    for (int j = 0; j < 4; ++j) { kw[j] = f2b(k0[j]); kw[4 + j] = f2b(k1[j]); }
    *(u16x8*)(&ldsK[0][kw_off]) = kw;
    #pragma unroll
    for (int jj = 0; jj < 2; ++jj) {
      const int row = vc + jj;
      u16x4 vw;
      vw[0] = f2b(v0[jj]); vw[1] = f2b(v1[jj]);
      vw[2] = f2b(v2[jj]); vw[3] = f2b(v3[jj]);
      *(u16x4*)(&ldsV[0][row * 64 + (((vq >> 1) ^ (row & 7)) << 3) + 4 * (vq & 1)]) = vw;
    }
  }
  __syncthreads();
  int cur = 0;

  for (int t = 0; t < nt; ++t) {
    const bool havenext = (t + 1 < nt);
    f32x4 k0, k1; f32x2 v0, v1, v2, v3;
    if (havenext) {          // T14: issue loads early, LDS-write late
      const float* Kn = Kp + (size_t)(t + 1) * 64 * HE;
      const float* Vn = Vp + (size_t)(t + 1) * 64 * HE;
      k0 = *(const f32x4*)(Kn);
      k1 = *(const f32x4*)(Kn + 4);
      v0 = *(const f32x2*)(Vn);
      v1 = *(const f32x2*)(Vn + HE);
      v2 = *(const f32x2*)(Vn + 2 * HE);
      v3 = *(const f32x2*)(Vn + 3 * HE);
    }

    if (t <= tmaxw) {
      const unsigned short* Kl = ldsK[cur];
      const unsigned short* Vl = ldsV[cur];

      // ---- S^T = K Q^T : 8 MFMAs ----
      f32x4 sacc[4];
      #pragma unroll
      for (int m = 0; m < 4; ++m) {
        sacc[m][0] = 0.f; sacc[m][1] = 0.f; sacc[m][2] = 0.f; sacc[m][3] = 0.f;
      }
      __builtin_amdgcn_s_setprio(1);
      #pragma unroll
      for (int ek = 0; ek < 2; ++ek) {
        #pragma unroll
        for (int m = 0; m < 4; ++m) {
          bf16x8 kf = *(const bf16x8*)(Kl + (16 * m + ll) * 64 +
                                       ((((ek << 2) + lg) ^ llm) << 3));
          sacc[m] = __builtin_amdgcn_mfma_f32_16x16x32_bf16(kf, qf[ek], sacc[m], 0, 0, 0);
        }
      }
      __builtin_amdgcn_s_setprio(0);

      // ---- causal mask (diagonal tile only) ----
      if (t == tmaxw) {
        const int dq = q0w + ll - 64 * t;   // keep kv_local <= dq
        #pragma unroll
        for (int m = 0; m < 4; ++m)
          #pragma unroll
          for (int r = 0; r < 4; ++r)
            if (16 * m + 4 * lg + r > dq) sacc[m][r] = -3.0e38f;
      }

      // ---- online softmax: balanced max tree + defer-max (T13) ----
      float t0 = fmaxf(fmaxf(sacc[0][0], sacc[0][1]), fmaxf(sacc[0][2], sacc[0][3]));
      float t1 = fmaxf(fmaxf(sacc[1][0], sacc[1][1]), fmaxf(sacc[1][2], sacc[1][3]));
      float t2 = fmaxf(fmaxf(sacc[2][0], sacc[2][1]), fmaxf(sacc[2][2], sacc[2][3]));
      float t3 = fmaxf(fmaxf(sacc[3][0], sacc[3][1]), fmaxf(sacc[3][2], sacc[3][3]));
      float mx = fmaxf(fmaxf(t0, t1), fmaxf(t2, t3));
      mx = fmaxf(mx, __shfl_xor(mx, 16));
      mx = fmaxf(mx, __shfl_xor(mx, 32));

      if (!__all(mx - m_run <= 8.0f)) {     // rescale needed (rare)
        const float mnew = fmaxf(m_run, mx);
        const float corr = exp2f(m_run - mnew);   // tile 0: exp2(-inf)=0
        m_run = mnew;
        l_run *= corr;
        #pragma unroll
        for (int r = 0; r < 4; ++r) {
          const float cr = __shfl(corr, 4 * lg + r);
          #pragma unroll
          for (int n = 0; n < 4; ++n) oacc[n][r] *= cr;
        }
      }

      #pragma unroll
      for (int m = 0; m < 4; ++m)
        #pragma unroll
        for (int r = 0; r < 4; ++r)
          sacc[m][r] = exp2f(sacc[m][r] - m_run);

      // balanced sum tree
      float s0 = (sacc[0][0] + sacc[0][1]) + (sacc[0][2] + sacc[0][3]);
      float s1 = (sacc[1][0] + sacc[1][1]) + (sacc[1][2] + sacc[1][3]);
      float s2 = (sacc[2][0] + sacc[2][1]) + (sacc[2][2] + sacc[2][3]);
      float s3 = (sacc[3][0] + sacc[3][1]) + (sacc[3][2] + sacc[3][3]);
      float rs = (s0 + s1) + (s2 + s3);
      rs += __shfl_xor(rs, 16);
      rs += __shfl_xor(rs, 32);
      l_run += rs;

      // ---- P frags: lane's own values, packed in permuted-kv order ----
      bf16x8 pf[2];
      #pragma unroll
      for (int ek = 0; ek < 2; ++ek)
        #pragma unroll
        for (int r = 0; r < 4; ++r) {
          pf[ek][r]     = (short)f2b(sacc[2 * ek][r]);
          pf[ek][4 + r] = (short)f2b(sacc[2 * ek + 1][r]);
        }

      // ---- O += P V : 8 MFMAs; V^T frags via union (no repack) ----
      __builtin_amdgcn_s_setprio(1);
      #pragma unroll
      for (int ek = 0; ek < 2; ++ek) {
        #pragma unroll
        for (int n = 0; n < 4; ++n) {
          const int d = 16 * n + ll;
          const int base = d * 64 + 4 * (lg & 1);
          union { bf16x8 v8; u16x4 q[2]; } vu;
          vu.q[0] = *(const u16x4*)(Vl + base +
                       ((((ek << 2) + (lg >> 1)) ^ llm) << 3));
          vu.q[1] = *(const u16x4*)(Vl + base +
                       ((((ek << 2) + 2 + (lg >> 1)) ^ llm) << 3));
          oacc[n] = __builtin_amdgcn_mfma_f32_16x16x32_bf16(pf[ek], vu.v8, oacc[n], 0, 0, 0);
        }
      }
      __builtin_amdgcn_s_setprio(0);
    }

    if (havenext) {
      const int nb = cur ^ 1;
      u16x8 kw;
      #pragma unroll
      for (int j = 0; j < 4; ++j) { kw[j] = f2b(k0[j]); kw[4 + j] = f2b(k1[j]); }
      *(u16x8*)(&ldsK[nb][kw_off]) = kw;
      #pragma unroll
      for (int jj = 0; jj < 2; ++jj) {
        const int row = vc + jj;
        u16x4 vw;
        vw[0] = f2b(v0[jj]); vw[1] = f2b(v1[jj]);
        vw[2] = f2b(v2[jj]); vw[3] = f2b(v3[jj]);
        *(u16x4*)(&ldsV[nb][row * 64 + (((vq >> 1) ^ (row & 7)) << 3) + 4 * (vq & 1)]) = vw;
      }
      __syncthreads();
      cur = nb;
    }
  }

  // ---- epilogue: normalize and store f32 ----
  const float linv = 1.0f / l_run;
  float* Ob = O + (((size_t)b * L_ + q0w) * H_ + h) * E_;
  #pragma unroll
  for (int r = 0; r < 4; ++r) {
    const float inv = __shfl(linv, 4 * lg + r);
    const int qrow = 4 * lg + r;
    #pragma unroll
    for (int n = 0; n < 4; ++n)
      Ob[(size_t)qrow * HE + 16 * n + ll] = oacc[n][r] * inv;
  }
}

extern "C" void kernel_launch(void* const* d_in, const int* in_sizes, int n_in,
                              void* d_out, int out_size, void* d_ws, size_t ws_size,
                              hipStream_t stream) {
  (void)in_sizes; (void)n_in; (void)out_size; (void)d_ws; (void)ws_size;
  const float* Q   = (const float*)d_in[0];
  const float* K   = (const float*)d_in[1];
  const float* V   = (const float*)d_in[2];
  // d_in[3] = attn_mask: ignored, causality applied analytically.
  const float* tau = (const float*)d_in[4];
  float* O = (float*)d_out;
  dim3 grid(L_ / 128, H_, B_), block(512);
  hipLaunchKernelGGL(attn_fwd, grid, block, 0, stream, Q, K, V, tau, O);
}

// Round 5
// 60.079 us; speedup vs baseline: 1.0030x; 1.0030x over previous
//
#include <hip/hip_runtime.h>
#include <hip/hip_bf16.h>
#include <math.h>

#define B_ 4
#define L_ 2048
#define H_ 8
#define E_ 64
#define HE 512   // H_*E_ : float stride between consecutive seq positions

typedef short bf16x8 __attribute__((ext_vector_type(8)));
typedef float f32x4 __attribute__((ext_vector_type(4)));
typedef float f32x16 __attribute__((ext_vector_type(16)));
typedef unsigned short u16x4 __attribute__((ext_vector_type(4)));
typedef unsigned short u16x8 __attribute__((ext_vector_type(8)));

__device__ __forceinline__ unsigned short f2b(float f) {
  return __builtin_bit_cast(unsigned short, (__hip_bfloat16)f);
}
__device__ __forceinline__ unsigned cvtpk(float lo, float hi) {
  unsigned r;
  asm("v_cvt_pk_bf16_f32 %0, %1, %2" : "=v"(r) : "v"(lo), "v"(hi));
  return r;
}
__device__ __forceinline__ void pl32swap(unsigned &a, unsigned &b) {
  asm volatile("v_permlane32_swap_b32 %0, %1" : "+v"(a), "+v"(b));
}

// Flash attention fwd, causal, tau-scaled.
// Block = 4 waves, 32 q-rows/wave (QBLK=128). KV tile 64, double-buffered.
// 32x32x16 MFMA: halves LDS bytes per q-row vs 16x16 (each wave reads the
// 16KB K+V tile for 32 q instead of 16). Swapped QK^T: sacc[mt][reg] =
// S[kv][q=lane&31]; softmax lane-local + 1 shfl. P routed to PV A-frags
// via 16 cvt_pk + 8 permlane32_swap (T12) -- no LDS round-trip.
__global__ __launch_bounds__(256, 2) void attn_fwd(
    const float* __restrict__ Q, const float* __restrict__ K,
    const float* __restrict__ V, const float* __restrict__ tau,
    float* __restrict__ O)
{
  // balanced remap: CU c gets flat {c, c+256} -> qt {j, 15-j}; (b,h) per
  // flat%32 -> all q-tiles of one (b,h) on one XCD.
  const int f  = blockIdx.x + 16 * (blockIdx.y + 8 * blockIdx.z);
  const int u  = f >> 5, hb = f & 31;
  const int h  = hb & 7, b = hb >> 3;
  const int qt = (u < 8) ? u : 23 - u;

  const int tid  = threadIdx.x;
  const int wave = tid >> 6, lane = tid & 63;
  const int l31 = lane & 31, hi = lane >> 5;
  const int l7 = l31 & 7;

  __shared__ unsigned short ldsK[2][64 * 64];  // [kv][e], XOR-16B swizzle
  __shared__ unsigned short ldsV[2][64 * 64];  // [d][kv], XOR-16B swizzle

  const float qscale = 0.125f * expf(tau[b]) * 1.44269504088896f;
  const int q0w = qt * 128 + wave * 32;        // wave's first q-row
  const int myq = q0w + l31;                   // this lane's q (dup over hi)

  // Q fragments (B operand): qf[ks][j] = Q[myq][16ks + 8hi + j]
  const float* Qb = Q + (((size_t)b * L_ + myq) * H_ + h) * E_;
  bf16x8 qf[4];
  #pragma unroll
  for (int ks = 0; ks < 4; ++ks) {
    f32x4 a = *(const f32x4*)(Qb + ks * 16 + hi * 8);
    f32x4 c = *(const f32x4*)(Qb + ks * 16 + hi * 8 + 4);
    #pragma unroll
    for (int j = 0; j < 4; ++j) {
      qf[ks][j]     = (short)f2b(a[j] * qscale);
      qf[ks][4 + j] = (short)f2b(c[j] * qscale);
    }
  }

  float m_run = -INFINITY, l_run = 0.0f;       // stats of q = myq
  f32x16 oacc[2];
  #pragma unroll
  for (int nd = 0; nd < 2; ++nd)
    #pragma unroll
    for (int r = 0; r < 16; ++r) oacc[nd][r] = 0.0f;

  // ---- staging maps (256 threads, 64B/thread for each of K and V) ----
  // K: row = tid>>2, col-group (tid&3)*16 : 4 f32x4 loads, 2 u16x8 writes
  // V: kv0 = (tid&15)*4, d0 = (tid>>4)*4 : 4 f32x4 loads, 4 u16x4 writes (T)
  const int krow = tid >> 2, kcg = tid & 3;
  const int vkv = (tid & 15) * 4, vd = (tid >> 4) * 4;
  const float* Kp = K + ((size_t)b * L_ * H_ + h) * E_ + (size_t)krow * HE + kcg * 16;
  const float* Vp = V + ((size_t)b * L_ * H_ + h) * E_ + (size_t)vkv * HE + vd;
  const int kwo0 = krow * 64 + (((2 * kcg) ^ (krow & 7)) << 3);
  const int kwo1 = krow * 64 + (((2 * kcg + 1) ^ (krow & 7)) << 3);

  const int nt = 2 * qt + 2;
  const int tmaxw = 2 * qt + (wave >> 1);      // wave's diagonal tile

  // ---- prologue: stage tile 0 into buf 0 ----
  {
    f32x4 kq[4], vq[4];
    #pragma unroll
    for (int i = 0; i < 4; ++i) kq[i] = *(const f32x4*)(Kp + 4 * i);
    #pragma unroll
    for (int i = 0; i < 4; ++i) vq[i] = *(const f32x4*)(Vp + (size_t)i * HE);
    u16x8 w0, w1;
    #pragma unroll
    for (int j = 0; j < 4; ++j) {
      w0[j] = f2b(kq[0][j]); w0[4 + j] = f2b(kq[1][j]);
      w1[j] = f2b(kq[2][j]); w1[4 + j] = f2b(kq[3][j]);
    }
    *(u16x8*)(&ldsK[0][kwo0]) = w0;
    *(u16x8*)(&ldsK[0][kwo1]) = w1;
    #pragma unroll
    for (int jd = 0; jd < 4; ++jd) {
      const int row = vd + jd;
      u16x4 vw;
      #pragma unroll
      for (int i = 0; i < 4; ++i) vw[i] = f2b(vq[i][jd]);
      *(u16x4*)(&ldsV[0][row * 64 + (((vkv >> 3) ^ (row & 7)) << 3) + (vkv & 7)]) = vw;
    }
  }
  __syncthreads();
  int cur = 0;

  for (int t = 0; t < nt; ++t) {
    const bool havenext = (t + 1 < nt);
    f32x4 kq[4], vq[4];
    if (havenext) {          // T14: issue next-tile loads early
      const float* Kn = Kp + (size_t)(t + 1) * 64 * HE;
      const float* Vn = Vp + (size_t)(t + 1) * 64 * HE;
      #pragma unroll
      for (int i = 0; i < 4; ++i) kq[i] = *(const f32x4*)(Kn + 4 * i);
      #pragma unroll
      for (int i = 0; i < 4; ++i) vq[i] = *(const f32x4*)(Vn + (size_t)i * HE);
    }

    if (t <= tmaxw) {
      const unsigned short* Kl = ldsK[cur];
      const unsigned short* Vl = ldsV[cur];

      // ---- S^T = K Q^T : 8 MFMAs (2 kv-subtiles x 4 k-steps) ----
      f32x16 sacc[2];
      #pragma unroll
      for (int mt = 0; mt < 2; ++mt)
        #pragma unroll
        for (int r = 0; r < 16; ++r) sacc[mt][r] = 0.0f;
      __builtin_amdgcn_s_setprio(1);
      #pragma unroll
      for (int ks = 0; ks < 4; ++ks) {
        #pragma unroll
        for (int mt = 0; mt < 2; ++mt) {
          bf16x8 kf = *(const bf16x8*)(Kl + (32 * mt + l31) * 64 +
                                       (((2 * ks + hi) ^ l7) << 3));
          sacc[mt] = __builtin_amdgcn_mfma_f32_32x32x16_bf16(kf, qf[ks], sacc[mt], 0, 0, 0);
        }
      }
      __builtin_amdgcn_s_setprio(0);

      // ---- causal mask (diagonal tile only) ----
      if (t == tmaxw) {
        const int dq = myq - 64 * t;     // keep kv_local <= dq
        const int kvhi = 4 * hi;
        #pragma unroll
        for (int mt = 0; mt < 2; ++mt)
          #pragma unroll
          for (int r = 0; r < 16; ++r) {
            const int kvl = (r & 3) + 8 * (r >> 2) + 32 * mt;
            if (kvl + kvhi > dq) sacc[mt][r] = -3.0e38f;
          }
      }

      // ---- online softmax: balanced max tree + defer-max (T13) ----
      float p0 = sacc[0][0], p1 = sacc[0][1], p2 = sacc[0][2], p3 = sacc[0][3];
      #pragma unroll
      for (int mt = 0; mt < 2; ++mt)
        #pragma unroll
        for (int r = (mt == 0 ? 4 : 0); r < 16; r += 4) {
          p0 = fmaxf(p0, sacc[mt][r]);
          p1 = fmaxf(p1, sacc[mt][r + 1]);
          p2 = fmaxf(p2, sacc[mt][r + 2]);
          p3 = fmaxf(p3, sacc[mt][r + 3]);
        }
      float mx = fmaxf(fmaxf(p0, p1), fmaxf(p2, p3));
      mx = fmaxf(mx, __shfl_xor(mx, 32));

      if (!__all(mx - m_run <= 8.0f)) {  // rescale needed (rare)
        const float mnew = fmaxf(m_run, mx);
        const float corr = exp2f(m_run - mnew);   // tile 0: exp2(-inf)=0
        m_run = mnew;
        l_run *= corr;
        #pragma unroll
        for (int r = 0; r < 16; ++r) {
          const int qrow = (r & 3) + 8 * (r >> 2) + 4 * hi;
          const float cr = __shfl(corr, qrow);
          oacc[0][r] *= cr;
          oacc[1][r] *= cr;
        }
      }

      float s0 = 0.f, s1 = 0.f, s2 = 0.f, s3 = 0.f;
      #pragma unroll
      for (int mt = 0; mt < 2; ++mt)
        #pragma unroll
        for (int r = 0; r < 16; r += 4) {
          float e0 = exp2f(sacc[mt][r]     - m_run);
          float e1 = exp2f(sacc[mt][r + 1] - m_run);
          float e2 = exp2f(sacc[mt][r + 2] - m_run);
          float e3 = exp2f(sacc[mt][r + 3] - m_run);
          sacc[mt][r] = e0; sacc[mt][r + 1] = e1;
          sacc[mt][r + 2] = e2; sacc[mt][r + 3] = e3;
          s0 += e0; s1 += e1; s2 += e2; s3 += e3;
        }
      float rs = (s0 + s1) + (s2 + s3);
      rs += __shfl_xor(rs, 32);
      l_run += rs;

      // ---- P -> A-frags: 16 cvt_pk + 8 permlane32_swap (T12) ----
      // pk[mt][i] packs sacc regs (2i, 2i+1). For frag ks (c=ks&1, mt=ks>>1):
      // swap(pk[4c], pk[4c+2]) -> j0j1 & j4j5 words; swap(pk[4c+1], pk[4c+3])
      // -> j2j3 & j6j7. Yields pf[ks][j] = P[myq][16ks + 8hi + j].
      unsigned pk0[8], pk1[8];
      #pragma unroll
      for (int i = 0; i < 8; ++i) pk0[i] = cvtpk(sacc[0][2 * i], sacc[0][2 * i + 1]);
      #pragma unroll
      for (int i = 0; i < 8; ++i) pk1[i] = cvtpk(sacc[1][2 * i], sacc[1][2 * i + 1]);
      bf16x8 pf[4];
      #pragma unroll
      for (int ks = 0; ks < 4; ++ks) {
        unsigned a  = (ks >> 1) ? pk1[4 * (ks & 1)]     : pk0[4 * (ks & 1)];
        unsigned y  = (ks >> 1) ? pk1[4 * (ks & 1) + 2] : pk0[4 * (ks & 1) + 2];
        unsigned a2 = (ks >> 1) ? pk1[4 * (ks & 1) + 1] : pk0[4 * (ks & 1) + 1];
        unsigned y2 = (ks >> 1) ? pk1[4 * (ks & 1) + 3] : pk0[4 * (ks & 1) + 3];
        pl32swap(a, y);
        pl32swap(a2, y2);
        union { unsigned w[4]; bf16x8 v; } pu;
        pu.w[0] = a; pu.w[1] = a2; pu.w[2] = y; pu.w[3] = y2;
        pf[ks] = pu.v;
      }

      // ---- O += P V : 8 MFMAs, V^T b128 reads ----
      __builtin_amdgcn_s_setprio(1);
      #pragma unroll
      for (int ks = 0; ks < 4; ++ks) {
        #pragma unroll
        for (int nd = 0; nd < 2; ++nd) {
          bf16x8 vf = *(const bf16x8*)(Vl + (32 * nd + l31) * 64 +
                                       (((2 * ks + hi) ^ l7) << 3));
          oacc[nd] = __builtin_amdgcn_mfma_f32_32x32x16_bf16(pf[ks], vf, oacc[nd], 0, 0, 0);
        }
      }
      __builtin_amdgcn_s_setprio(0);
    }

    if (havenext) {
      const int nb = cur ^ 1;
      u16x8 w0, w1;
      #pragma unroll
      for (int j = 0; j < 4; ++j) {
        w0[j] = f2b(kq[0][j]); w0[4 + j] = f2b(kq[1][j]);
        w1[j] = f2b(kq[2][j]); w1[4 + j] = f2b(kq[3][j]);
      }
      *(u16x8*)(&ldsK[nb][kwo0]) = w0;
      *(u16x8*)(&ldsK[nb][kwo1]) = w1;
      #pragma unroll
      for (int jd = 0; jd < 4; ++jd) {
        const int row = vd + jd;
        u16x4 vw;
        #pragma unroll
        for (int i = 0; i < 4; ++i) vw[i] = f2b(vq[i][jd]);
        *(u16x4*)(&ldsV[nb][row * 64 + (((vkv >> 3) ^ (row & 7)) << 3) + (vkv & 7)]) = vw;
      }
      __syncthreads();
      cur = nb;
    }
  }

  // ---- epilogue: normalize and store f32 ----
  const float linv = 1.0f / l_run;             // valid per q = myq
  float* Ob = O + (((size_t)b * L_ + q0w) * H_ + h) * E_;
  #pragma unroll
  for (int r = 0; r < 16; ++r) {
    const int qrow = (r & 3) + 8 * (r >> 2) + 4 * hi;
    const float inv = __shfl(linv, qrow);
    Ob[(size_t)qrow * HE + l31]      = oacc[0][r] * inv;
    Ob[(size_t)qrow * HE + 32 + l31] = oacc[1][r] * inv;
  }
}

extern "C" void kernel_launch(void* const* d_in, const int* in_sizes, int n_in,
                              void* d_out, int out_size, void* d_ws, size_t ws_size,
                              hipStream_t stream) {
  (void)in_sizes; (void)n_in; (void)out_size; (void)d_ws; (void)ws_size;
  const float* Q   = (const float*)d_in[0];
  const float* K   = (const float*)d_in[1];
  const float* V   = (const float*)d_in[2];
  // d_in[3] = attn_mask: ignored, causality applied analytically.
  const float* tau = (const float*)d_in[4];
  float* O = (float*)d_out;
  dim3 grid(L_ / 128, H_, B_), block(256);
  hipLaunchKernelGGL(attn_fwd, grid, block, 0, stream, Q, K, V, tau, O);
}